// Round 1
// baseline (196.709 us; speedup 1.0000x reference)
//
#include <hip/hip_runtime.h>
#include <math.h>

#define R_N 4096
#define D_N 4096
#define C_N 20
#define IMG_W_F 1216.0f
#define IMG_H_F 800.0f
#define SCORE_TH 0.05f
#define NMS_TH 0.5f
#define TOPK_N 100

typedef short bf16x8 __attribute__((ext_vector_type(8)));
typedef float f32x4  __attribute__((ext_vector_type(4)));

// self-resetting cross-launch counter: zero-init at module load; the finishing
// block stores 0 at the end of every launch, so the invariant holds across
// warmup + timed iterations + rocprof replays.
__device__ int g_done;

// truncating bf16 pack: {hi16(a), hi16(b)} -> lo short = bf16(b), hi short = bf16(a)
__device__ __forceinline__ unsigned pk(float a, float b) {
  return __builtin_amdgcn_perm(__float_as_uint(a), __float_as_uint(b), 0x07060302u);
}
__device__ __forceinline__ float fexp(float x) { return __expf(x); }

__device__ __forceinline__ void load_clip_box(const float* boxes, int r, float* b) {
  b[0] = fminf(fmaxf(boxes[r * 4 + 0], 0.f), IMG_W_F);
  b[1] = fminf(fmaxf(boxes[r * 4 + 1], 0.f), IMG_H_F);
  b[2] = fminf(fmaxf(boxes[r * 4 + 2], 0.f), IMG_W_F);
  b[3] = fminf(fmaxf(boxes[r * 4 + 3], 0.f), IMG_H_F);
}

// ============ single fused kernel ============
// 256 blocks x 1024 threads (16 waves). Block = 16 rows, wave w owns K slice
// [w*256,(w+1)*256). Per K-chunk of 32, the wave stages the contiguous
// W_det slice (32 rows x 21 cols = 672 floats) into private LDS, then builds
// bf16 B-fragments with scalar ds_reads (2-way bank alias = free).
// Epilogue: 16-way LDS reduce -> detlog. Done-counter: last block computes
// det-softmax denominators, candidates, on-demand cls GEMV, NMS, top-100.
__global__ __launch_bounds__(1024) void fused_kernel(
    const float* __restrict__ x, const float* __restrict__ Wd,
    const float* __restrict__ Wc, const float* __restrict__ b_cls,
    const float* __restrict__ boxes,
    float* __restrict__ detlog, float* __restrict__ out) {
  // GEMM phase: WB = 16 waves * 672 floats = 43008 B. Reused afterwards for
  // red[16*512] (32 KB) and then the finisher's scratch.
  __shared__ float smem[10752];
  __shared__ int s_lastf;

  const int t = threadIdx.x;
  const int w = t >> 6, l = t & 63;
  const int r16 = l & 15, q = l >> 4;
  const int r0 = blockIdx.x * 16;

  // ---- prefetch all A (16 rows x 256 K for this wave): 16 outstanding loads ----
  const float* xrow = x + (size_t)(r0 + r16) * D_N + w * 256 + q * 8;
  float4 a[16];
#pragma unroll
  for (int s = 0; s < 8; s++) {
    a[2 * s]     = *(const float4*)(xrow + s * 32);
    a[2 * s + 1] = *(const float4*)(xrow + s * 32 + 4);
  }

  float* wb = smem + w * 672;                       // per-wave private W slice
  const int c0  = l & 15;                           // ct=0 col
  const bool v1 = (c0 < 5);                         // ct=1 col valid (16+c0 < 21)
  const int cc1 = v1 ? (16 + c0) : 0;               // clamped in-bounds address
  const int rb  = q * 8;

  f32x4 acc0 = {0.f, 0.f, 0.f, 0.f};
  f32x4 acc1 = {0.f, 0.f, 0.f, 0.f};
#pragma unroll
  for (int s = 0; s < 8; s++) {
    // stage W rows [w*256+s*32, +32) x 21 cols = 672 contiguous floats
    const float* p = Wd + (size_t)((w * 256 + s * 32) * 21);
    float4 w0 = *(const float4*)(p + 4 * l);
    float4 w1 = *(const float4*)(p + 4 * l + 256);
    *(float4*)(wb + 4 * l)       = w0;
    *(float4*)(wb + 4 * l + 256) = w1;
    if (l < 40) {
      float4 w2 = *(const float4*)(p + 4 * l + 512);
      *(float4*)(wb + 4 * l + 512) = w2;
    }
    // build B frags: lane holds B[k=rb+j][col]  (same layout the old wT packed)
    union { bf16x8 v; unsigned u[4]; } b0, b1, af;
#pragma unroll
    for (int jj = 0; jj < 4; jj++) {
      float e0 = wb[(rb + 2 * jj)     * 21 + c0];
      float e1 = wb[(rb + 2 * jj + 1) * 21 + c0];
      b0.u[jj] = pk(e1, e0);
      float f0 = wb[(rb + 2 * jj)     * 21 + cc1];
      float f1 = wb[(rb + 2 * jj + 1) * 21 + cc1];
      unsigned uu = pk(f1, f0);
      b1.u[jj] = v1 ? uu : 0u;
    }
    af.u[0] = pk(a[2 * s].y,     a[2 * s].x);
    af.u[1] = pk(a[2 * s].w,     a[2 * s].z);
    af.u[2] = pk(a[2 * s + 1].y, a[2 * s + 1].x);
    af.u[3] = pk(a[2 * s + 1].w, a[2 * s + 1].z);
    acc0 = __builtin_amdgcn_mfma_f32_16x16x32_bf16(af.v, b0.v, acc0, 0, 0, 0);
    acc1 = __builtin_amdgcn_mfma_f32_16x16x32_bf16(af.v, b1.v, acc1, 0, 0, 0);
  }

  // ---- epilogue: 16-way reduce; lane l, reg j holds D[row=q*4+j][col=ct*16+r16]
  __syncthreads();                                  // WB dead; reuse as red
  float* red = smem;                                // [16][512], o = c*16 + r
  *(f32x4*)(&red[w * 512 + (0  + r16) * 16 + q * 4]) = acc0;
  *(f32x4*)(&red[w * 512 + (16 + r16) * 16 + q * 4]) = acc1;
  __syncthreads();
  if (t < 512) {
    float v = 0.f;
#pragma unroll
    for (int w2 = 0; w2 < 16; w2++) v += red[w2 * 512 + t];
    red[t] = v;
  }
  __syncthreads();
  if (t < 21) {
#pragma unroll
    for (int r = 0; r < 16; r++)
      detlog[(size_t)(r0 + r) * 24 + t] = red[t * 16 + r];
  }

  // ---- done-counter: release stores, last block proceeds ----
  __threadfence();
  __syncthreads();
  if (t == 0) s_lastf = (atomicAdd(&g_done, 1) == 255) ? 1 : 0;
  __syncthreads();
  if (!s_lastf) return;
  __threadfence();

  // ================== finisher (last block only, 1024 threads) ==================
  float* sd     = smem;                             // 20
  int*   nc_l   = (int*)(smem + 32);                // 20
  int*   cand_r = (int*)(smem + 64);                // 640
  float* cand_d = smem + 704;                       // 640
  float* cand_s = smem + 1344;                      // 640
  int*   s_ki   = (int*)(smem + 1984);              // 512
  float* s_ks   = smem + 2496;                      // 512
  float* sval   = smem + 3008;                      // 100
  int*   sidx   = (int*)(smem + 3108);              // 100
  float* wred   = smem + 3208;                      // 16*20 wave partials
  int*   s_kc   = (int*)(smem + 3528);

  // ---- pass A: per-class exp-sums over all 4096 rows ----
  float ps[20];
#pragma unroll
  for (int c = 0; c < 20; c++) ps[c] = 0.f;
  for (int rr = t; rr < R_N; rr += 1024) {
    const float* dp = detlog + (size_t)rr * 24;
    union { float4 v[5]; float f[20]; } u;
    u.v[0] = *(const float4*)(dp + 0);
    u.v[1] = *(const float4*)(dp + 4);
    u.v[2] = *(const float4*)(dp + 8);
    u.v[3] = *(const float4*)(dp + 12);
    u.v[4] = *(const float4*)(dp + 16);
#pragma unroll
    for (int c = 0; c < 20; c++) ps[c] += fexp(u.f[c]);
  }
#pragma unroll
  for (int c = 0; c < 20; c++) {
    float v = ps[c];
#pragma unroll
    for (int off = 32; off; off >>= 1) v += __shfl_xor(v, off, 64);
    ps[c] = v;
  }
  if (l == 0) {
#pragma unroll
    for (int c = 0; c < 20; c++) wred[w * 20 + c] = ps[c];
  }
  __syncthreads();
  if (t < 20) {
    float v = 0.f;
#pragma unroll
    for (int w2 = 0; w2 < 16; w2++) v += wred[w2 * 20 + t];
    sd[t] = v;
    nc_l[t] = 0;
  }
  if (t == 0) *s_kc = 0;
  if (t < TOPK_N) { sval[t] = 0.f; sidx[t] = 0; }
  __syncthreads();

  // ---- pass B: det-softmax candidates (superset of score>TH since cls_sm<=1) ----
  for (int rr = t; rr < R_N; rr += 1024) {
    const float* dp = detlog + (size_t)rr * 24;
    union { float4 v[5]; float f[20]; } u;
    u.v[0] = *(const float4*)(dp + 0);
    u.v[1] = *(const float4*)(dp + 4);
    u.v[2] = *(const float4*)(dp + 8);
    u.v[3] = *(const float4*)(dp + 12);
    u.v[4] = *(const float4*)(dp + 16);
#pragma unroll
    for (int c = 0; c < 20; c++) {
      float dsm = fexp(u.f[c]) / sd[c];
      if (dsm > SCORE_TH) {
        int p = atomicAdd(&nc_l[c], 1);
        if (p < 32) { cand_r[c * 32 + p] = rr; cand_d[c * 32 + p] = dsm; }
      }
    }
  }
  __syncthreads();

  // ---- exact scores for candidates (cls logits on demand) ----
  for (int slot = t; slot < 640; slot += 1024) {
    const int c = slot >> 5, i = slot & 31;
    int n = nc_l[c]; if (n > 32) n = 32;
    if (i < n) {
      const int rr = cand_r[slot];
      float lg[21];
#pragma unroll
      for (int j = 0; j < 21; j++) lg[j] = b_cls[j];
      const float* xr = x + (size_t)rr * D_N;
      for (int k = 0; k < D_N; k++) {
        float xv = xr[k];
        const float* wr = Wc + (size_t)k * 21;
#pragma unroll
        for (int j = 0; j < 21; j++) lg[j] = fmaf(xv, wr[j], lg[j]);
      }
      float m = -1e30f;
#pragma unroll
      for (int j = 0; j < 21; j++) m = fmaxf(m, lg[j]);
      float s = 0.f;
#pragma unroll
      for (int j = 0; j < 21; j++) s += fexp(lg[j] - m);
      float p = fexp(lg[c] - m) / s;
      cand_s[slot] = p * cand_d[slot];
    }
  }
  __syncthreads();

  // ---- per-class NMS on score>TH candidates ----
  if (t < 20) {
    const int c = t;
    int n = nc_l[c]; if (n > 32) n = 32;
    float s[32]; int rr[32]; int n2 = 0;
    for (int i = 0; i < n; i++) {
      float sc = cand_s[c * 32 + i];
      if (sc > SCORE_TH) { s[n2] = sc; rr[n2] = cand_r[c * 32 + i]; n2++; }
    }
    for (int i = 1; i < n2; i++) {                  // score desc, tie -> row asc
      float si = s[i]; int ri = rr[i];
      int j = i - 1;
      while (j >= 0 && (s[j] < si || (s[j] == si && rr[j] > ri))) {
        s[j + 1] = s[j]; rr[j + 1] = rr[j]; j--;
      }
      s[j + 1] = si; rr[j + 1] = ri;
    }
    unsigned supp = 0;
    for (int i = 0; i < n2; i++) {
      if (supp & (1u << i)) continue;
      int g = atomicAdd(s_kc, 1);
      if (g < 512) { s_ki[g] = rr[i] * C_N + c; s_ks[g] = s[i]; }
      float bi[4]; load_clip_box(boxes, rr[i], bi);
      float ai = (bi[2] - bi[0]) * (bi[3] - bi[1]);
      for (int j = i + 1; j < n2; j++) {
        if (supp & (1u << j)) continue;
        float bj[4]; load_clip_box(boxes, rr[j], bj);
        float aj = (bj[2] - bj[0]) * (bj[3] - bj[1]);
        float lx = fmaxf(bi[0], bj[0]), ly = fmaxf(bi[1], bj[1]);
        float rx = fminf(bi[2], bj[2]), ry = fminf(bi[3], bj[3]);
        float wdt = fmaxf(rx - lx, 0.f), hgt = fmaxf(ry - ly, 0.f);
        float inter = wdt * hgt;
        float iou = inter / (ai + aj - inter + 1e-9f);
        if (iou > NMS_TH) supp |= (1u << j);
      }
    }
  }
  __syncthreads();

  // ---- top-100 with jax.lax.top_k tie rules ----
  int m = *s_kc; if (m > 512) m = 512;
  for (int i = t; i < m; i += 1024) {
    float si = s_ks[i]; int xi = s_ki[i];
    int rank = 0;
    for (int j = 0; j < m; j++) {
      float sj = s_ks[j]; int xj = s_ki[j];
      if (sj > si || (sj == si && xj < xi)) rank++;
    }
    if (rank < TOPK_N) { sval[rank] = si; sidx[rank] = xi; }
  }
  __syncthreads();
  if (t == 0) {
    int f = m < TOPK_N ? m : TOPK_N;
    int cur = 0;
    for (int slot = f; slot < TOPK_N; slot++) {
      for (;;) {
        bool member = false;
        for (int j = 0; j < m; j++)
          if (s_ki[j] == cur) { member = true; break; }
        if (!member) break;
        cur++;
      }
      sval[slot] = 0.f;
      sidx[slot] = cur;
      cur++;
    }
  }
  __syncthreads();
  if (t < TOPK_N) {
    int idx = sidx[t];
    int prop = idx / C_N;
    int cls = idx - prop * C_N;
    float b[4]; load_clip_box(boxes, prop, b);
    out[t] = sval[t];
    out[TOPK_N + t * 4 + 0] = b[0];
    out[TOPK_N + t * 4 + 1] = b[1];
    out[TOPK_N + t * 4 + 2] = b[2];
    out[TOPK_N + t * 4 + 3] = b[3];
    out[TOPK_N * 5 + t] = (float)cls;
  }
  if (t == 0) g_done = 0;                           // re-arm for next launch
}

extern "C" void kernel_launch(void* const* d_in, const int* in_sizes, int n_in,
                              void* d_out, int out_size, void* d_ws, size_t ws_size,
                              hipStream_t stream) {
  const float* x     = (const float*)d_in[0];
  const float* boxes = (const float*)d_in[1];
  const float* W_cls = (const float*)d_in[2];
  const float* b_cls = (const float*)d_in[3];
  const float* W_det = (const float*)d_in[4];
  // b_det unused: column-softmax bias cancels

  float* out    = (float*)d_out;
  float* detlog = (float*)d_ws;                     // 4096 x 24 f32 (cols 0..20 valid)

  fused_kernel<<<256, 1024, 0, stream>>>(x, W_det, W_cls, b_cls, boxes, detlog, out);
}

// Round 2
// 134.826 us; speedup vs baseline: 1.4590x; 1.4590x over previous
//
#include <hip/hip_runtime.h>
#include <math.h>

#define R_N 4096
#define D_N 4096
#define C_N 20
#define IMG_W_F 1216.0f
#define IMG_H_F 800.0f
#define SCORE_TH 0.05f
#define NMS_TH 0.5f
#define TOPK_N 100

// ---- workspace layout (units: 4-byte words) ----
// Wfrag: 128 gs x 2 ct x 64 lanes x 16 B = 256 KB (det cols 0..20, 21..31 zero)
#define WF_WORDS   (128 * 2 * 64 * 4)                // 65536
#define DET_OFF    (WF_WORDS)                        // detlog[4096][24] f32 (cols 0..20 valid)

typedef short bf16x8 __attribute__((ext_vector_type(8)));
typedef float f32x4  __attribute__((ext_vector_type(4)));

// truncating bf16 pack: {hi16(a), hi16(b)} -> lo short = bf16(b), hi short = bf16(a)
__device__ __forceinline__ unsigned pk(float a, float b) {
  return __builtin_amdgcn_perm(__float_as_uint(a), __float_as_uint(b), 0x07060302u);
}
__device__ __forceinline__ float fexp(float x) { return __expf(x); }

__device__ __forceinline__ void load_clip_box(const float* boxes, int r, float* b) {
  b[0] = fminf(fmaxf(boxes[r * 4 + 0], 0.f), IMG_W_F);
  b[1] = fminf(fmaxf(boxes[r * 4 + 1], 0.f), IMG_H_F);
  b[2] = fminf(fmaxf(boxes[r * 4 + 2], 0.f), IMG_W_F);
  b[3] = fminf(fmaxf(boxes[r * 4 + 3], 0.f), IMG_H_F);
}

// ============ pack W_det -> frag-linear bf16; zero detlog ============
// entry e: l=e&63, ct=(e>>6)&1, gs=e>>7
// holds B[k = gs*32 + (l>>4)*8 + j][col = ct*16 + (l&15)], j=0..7
__global__ __launch_bounds__(256) void wT_kernel(
    const float* __restrict__ Wd, uint4* __restrict__ Wfrag,
    float* __restrict__ detlog) {
  const int e = blockIdx.x * 256 + threadIdx.x;     // 64 blocks -> 16384
  const int l = e & 63;
  const int ct = (e >> 6) & 1;
  const int gs = e >> 7;
  const int c = ct * 16 + (l & 15);
  const int k0 = gs * 32 + (l >> 4) * 8;
  float w[8];
  if (c < 21) {
#pragma unroll
    for (int j = 0; j < 8; j++) w[j] = Wd[(size_t)(k0 + j) * 21 + c];
  } else {
#pragma unroll
    for (int j = 0; j < 8; j++) w[j] = 0.f;
  }
  uint4 v;
  v.x = pk(w[1], w[0]); v.y = pk(w[3], w[2]);
  v.z = pk(w[5], w[4]); v.w = pk(w[7], w[6]);
  Wfrag[(gs * 2 + ct) * 64 + l] = v;
  // zero detlog for atomic accumulation (4096*24 = 98304 words, 6 per thread)
#pragma unroll
  for (int i = e; i < R_N * 24; i += 16384) detlog[i] = 0.f;
}

// ============ det GEMM, 2-way K-split ============
// 512 blocks x 1024 thr (16 waves). Block (rblk,kb): rows [rblk*16,+16),
// K half kb. Wave w: K chunk [kb*2048 + w*128, +128). A: all 8 float4 loads
// issued up-front. B: frag-linear from L2. No barriers, no fences in K-loop.
// Epilogue: in-block 16-way LDS reduce -> f32 atomicAdd into detlog
// (exactly 2 commutative adds per cell -> deterministic).
__global__ __launch_bounds__(1024) void detgemm_kernel(
    const float* __restrict__ x, const uint4* __restrict__ Wfrag,
    float* __restrict__ detlog) {
  __shared__ float red[16 * 512];                   // 32 KB
  const int t = threadIdx.x;
  const int w = t >> 6, l = t & 63;
  const int r16 = l & 15, q = l >> 4;
  const int rblk = blockIdx.x >> 1;
  const int kb   = blockIdx.x & 1;
  const int r0 = rblk * 16;

  const float* xrow = x + (size_t)(r0 + r16) * D_N + kb * 2048 + w * 128 + q * 8;

  // ---- prefetch all A (this wave's 16 rows x 128 K): 8 outstanding loads ----
  float4 a[8];
#pragma unroll
  for (int s = 0; s < 4; s++) {
    a[2 * s]     = *(const float4*)(xrow + s * 32);
    a[2 * s + 1] = *(const float4*)(xrow + s * 32 + 4);
  }

  f32x4 acc0 = {0.f, 0.f, 0.f, 0.f};
  f32x4 acc1 = {0.f, 0.f, 0.f, 0.f};
#pragma unroll
  for (int s = 0; s < 4; s++) {
    const int gs = kb * 64 + w * 4 + s;
    union { uint4 u; bf16x8 v; } b0, b1;
    b0.u = Wfrag[(gs * 2 + 0) * 64 + l];
    b1.u = Wfrag[(gs * 2 + 1) * 64 + l];
    union { bf16x8 v; unsigned u[4]; } af;
    af.u[0] = pk(a[2 * s].y,     a[2 * s].x);
    af.u[1] = pk(a[2 * s].w,     a[2 * s].z);
    af.u[2] = pk(a[2 * s + 1].y, a[2 * s + 1].x);
    af.u[3] = pk(a[2 * s + 1].w, a[2 * s + 1].z);
    acc0 = __builtin_amdgcn_mfma_f32_16x16x32_bf16(af.v, b0.v, acc0, 0, 0, 0);
    acc1 = __builtin_amdgcn_mfma_f32_16x16x32_bf16(af.v, b1.v, acc1, 0, 0, 0);
  }

  // lane l, reg j holds D[row = q*4+j][col = ct*16 + r16]; red layout [w][c][r]
  *(f32x4*)(&red[w * 512 + (0  + r16) * 16 + q * 4]) = acc0;
  *(f32x4*)(&red[w * 512 + (16 + r16) * 16 + q * 4]) = acc1;
  __syncthreads();
  if (t < 336) {                                    // t = c*16 + r, c<21
    float v = 0.f;
#pragma unroll
    for (int w2 = 0; w2 < 16; w2++) v += red[w2 * 512 + t];
    atomicAdd(&detlog[(size_t)(r0 + (t & 15)) * 24 + (t >> 4)], v);
  }
}

// ============ finish: single block, no fences ============
// Pass A: per-class exp-sums over detlog (393 KB). Pass B: det-softmax
// candidates (superset of score>TH since cls_sm<=1). Then exact scores via
// on-demand cls GEMV, per-class NMS, top-100.
__global__ __launch_bounds__(1024) void finish_kernel(
    const float* __restrict__ x, const float* __restrict__ Wc,
    const float* __restrict__ b_cls, const float* __restrict__ detlog,
    const float* __restrict__ boxes, float* __restrict__ out) {
  __shared__ float sd[20];
  __shared__ float wred[16 * 20];
  __shared__ int   nc[20];
  __shared__ int   cand_r[640];
  __shared__ float cand_d[640];
  __shared__ float cand_s[640];
  __shared__ int   s_ki[512];
  __shared__ float s_ks[512];
  __shared__ float sval[TOPK_N];
  __shared__ int   sidx[TOPK_N];
  __shared__ int   s_kc;
  const int t = threadIdx.x;
  const int w = t >> 6, l = t & 63;

  // ---- pass A: per-class exp-sums over all 4096 rows ----
  float ps[20];
#pragma unroll
  for (int c = 0; c < 20; c++) ps[c] = 0.f;
  for (int rr = t; rr < R_N; rr += 1024) {
    const float* dp = detlog + (size_t)rr * 24;
    union { float4 v[5]; float f[20]; } u;
    u.v[0] = *(const float4*)(dp + 0);
    u.v[1] = *(const float4*)(dp + 4);
    u.v[2] = *(const float4*)(dp + 8);
    u.v[3] = *(const float4*)(dp + 12);
    u.v[4] = *(const float4*)(dp + 16);
#pragma unroll
    for (int c = 0; c < 20; c++) ps[c] += fexp(u.f[c]);
  }
#pragma unroll
  for (int c = 0; c < 20; c++) {
    float v = ps[c];
#pragma unroll
    for (int off = 32; off; off >>= 1) v += __shfl_xor(v, off, 64);
    ps[c] = v;
  }
  if (l == 0) {
#pragma unroll
    for (int c = 0; c < 20; c++) wred[w * 20 + c] = ps[c];
  }
  __syncthreads();
  if (t < 20) {
    float v = 0.f;
#pragma unroll
    for (int w2 = 0; w2 < 16; w2++) v += wred[w2 * 20 + t];
    sd[t] = v;
    nc[t] = 0;
  }
  if (t == 0) s_kc = 0;
  if (t < TOPK_N) { sval[t] = 0.f; sidx[t] = 0; }
  __syncthreads();

  // ---- pass B: det-softmax candidates ----
  for (int rr = t; rr < R_N; rr += 1024) {
    const float* dp = detlog + (size_t)rr * 24;
    union { float4 v[5]; float f[20]; } u;
    u.v[0] = *(const float4*)(dp + 0);
    u.v[1] = *(const float4*)(dp + 4);
    u.v[2] = *(const float4*)(dp + 8);
    u.v[3] = *(const float4*)(dp + 12);
    u.v[4] = *(const float4*)(dp + 16);
#pragma unroll
    for (int c = 0; c < 20; c++) {
      float dsm = fexp(u.f[c]) / sd[c];
      if (dsm > SCORE_TH) {
        int p = atomicAdd(&nc[c], 1);
        if (p < 32) { cand_r[c * 32 + p] = rr; cand_d[c * 32 + p] = dsm; }
      }
    }
  }
  __syncthreads();

  // ---- exact scores for candidates (cls logits on demand) ----
  for (int slot = t; slot < 640; slot += 1024) {
    const int c = slot >> 5, i = slot & 31;
    int n = nc[c]; if (n > 32) n = 32;
    if (i < n) {
      const int rr = cand_r[slot];
      float lg[21];
#pragma unroll
      for (int j = 0; j < 21; j++) lg[j] = b_cls[j];
      const float* xr = x + (size_t)rr * D_N;
      for (int k = 0; k < D_N; k++) {
        float xv = xr[k];
        const float* wr = Wc + (size_t)k * 21;
#pragma unroll
        for (int j = 0; j < 21; j++) lg[j] = fmaf(xv, wr[j], lg[j]);
      }
      float m = -1e30f;
#pragma unroll
      for (int j = 0; j < 21; j++) m = fmaxf(m, lg[j]);
      float s = 0.f;
#pragma unroll
      for (int j = 0; j < 21; j++) s += fexp(lg[j] - m);
      float p = fexp(lg[c] - m) / s;
      cand_s[slot] = p * cand_d[slot];
    }
  }
  __syncthreads();

  // ---- per-class NMS on score>TH candidates ----
  if (t < 20) {
    const int c = t;
    int n = nc[c]; if (n > 32) n = 32;
    float s[32]; int rr[32]; int n2 = 0;
    for (int i = 0; i < n; i++) {
      float sc = cand_s[c * 32 + i];
      if (sc > SCORE_TH) { s[n2] = sc; rr[n2] = cand_r[c * 32 + i]; n2++; }
    }
    for (int i = 1; i < n2; i++) {                  // score desc, tie -> row asc
      float si = s[i]; int ri = rr[i];
      int j = i - 1;
      while (j >= 0 && (s[j] < si || (s[j] == si && rr[j] > ri))) {
        s[j + 1] = s[j]; rr[j + 1] = rr[j]; j--;
      }
      s[j + 1] = si; rr[j + 1] = ri;
    }
    unsigned supp = 0;
    for (int i = 0; i < n2; i++) {
      if (supp & (1u << i)) continue;
      int g = atomicAdd(&s_kc, 1);
      if (g < 512) { s_ki[g] = rr[i] * C_N + c; s_ks[g] = s[i]; }
      float bi[4]; load_clip_box(boxes, rr[i], bi);
      float ai = (bi[2] - bi[0]) * (bi[3] - bi[1]);
      for (int j = i + 1; j < n2; j++) {
        if (supp & (1u << j)) continue;
        float bj[4]; load_clip_box(boxes, rr[j], bj);
        float aj = (bj[2] - bj[0]) * (bj[3] - bj[1]);
        float lx = fmaxf(bi[0], bj[0]), ly = fmaxf(bi[1], bj[1]);
        float rx = fminf(bi[2], bj[2]), ry = fminf(bi[3], bj[3]);
        float wdt = fmaxf(rx - lx, 0.f), hgt = fmaxf(ry - ly, 0.f);
        float inter = wdt * hgt;
        float iou = inter / (ai + aj - inter + 1e-9f);
        if (iou > NMS_TH) supp |= (1u << j);
      }
    }
  }
  __syncthreads();

  // ---- top-100 with jax.lax.top_k tie rules ----
  int m = s_kc; if (m > 512) m = 512;
  for (int i = t; i < m; i += 1024) {
    float si = s_ks[i]; int xi = s_ki[i];
    int rank = 0;
    for (int j = 0; j < m; j++) {
      float sj = s_ks[j]; int xj = s_ki[j];
      if (sj > si || (sj == si && xj < xi)) rank++;
    }
    if (rank < TOPK_N) { sval[rank] = si; sidx[rank] = xi; }
  }
  __syncthreads();
  if (t == 0) {
    int f = m < TOPK_N ? m : TOPK_N;
    int cur = 0;
    for (int slot = f; slot < TOPK_N; slot++) {
      for (;;) {
        bool member = false;
        for (int j = 0; j < m; j++)
          if (s_ki[j] == cur) { member = true; break; }
        if (!member) break;
        cur++;
      }
      sval[slot] = 0.f;
      sidx[slot] = cur;
      cur++;
    }
  }
  __syncthreads();
  if (t < TOPK_N) {
    int idx = sidx[t];
    int prop = idx / C_N;
    int cls = idx - prop * C_N;
    float b[4]; load_clip_box(boxes, prop, b);
    out[t] = sval[t];
    out[TOPK_N + t * 4 + 0] = b[0];
    out[TOPK_N + t * 4 + 1] = b[1];
    out[TOPK_N + t * 4 + 2] = b[2];
    out[TOPK_N + t * 4 + 3] = b[3];
    out[TOPK_N * 5 + t] = (float)cls;
  }
}

extern "C" void kernel_launch(void* const* d_in, const int* in_sizes, int n_in,
                              void* d_out, int out_size, void* d_ws, size_t ws_size,
                              hipStream_t stream) {
  const float* x     = (const float*)d_in[0];
  const float* boxes = (const float*)d_in[1];
  const float* W_cls = (const float*)d_in[2];
  const float* b_cls = (const float*)d_in[3];
  const float* W_det = (const float*)d_in[4];
  // b_det unused: column-softmax bias cancels

  float* out = (float*)d_out;
  float* ws = (float*)d_ws;
  uint4* Wfrag  = (uint4*)ws;
  float* detlog = ws + DET_OFF;

  wT_kernel     <<<64,  256,  0, stream>>>(W_det, Wfrag, detlog);
  detgemm_kernel<<<512, 1024, 0, stream>>>(x, Wfrag, detlog);
  finish_kernel <<<1,   1024, 0, stream>>>(x, W_cls, b_cls, detlog, boxes, out);
}

// Round 3
// 120.285 us; speedup vs baseline: 1.6354x; 1.1209x over previous
//
#include <hip/hip_runtime.h>
#include <math.h>

#define R_N 4096
#define D_N 4096
#define C_N 20
#define IMG_W_F 1216.0f
#define IMG_H_F 800.0f
#define SCORE_TH 0.05f
#define NMS_TH 0.5f
#define TOPK_N 100

// ---- workspace layout (units: 4-byte words) ----
// Wfrag: 128 gs x 2 ct x 64 lanes x 16 B = 256 KB (det cols 0..20, 21..31 zero)
#define WF_WORDS   (128 * 2 * 64 * 4)                // 65536
#define CTRL_OFF   (WF_WORDS)                        // dsum f32[20] | nc i32[20] | done1 | done2 (42 words, pad to 64)
#define CAND_R_OFF (CTRL_OFF + 64)                   // i32[640]
#define CAND_D_OFF (CAND_R_OFF + 640)                // f32[640]

typedef short bf16x8 __attribute__((ext_vector_type(8)));
typedef float f32x4  __attribute__((ext_vector_type(4)));

// truncating bf16 pack: {hi16(a), hi16(b)} -> lo short = bf16(b), hi short = bf16(a)
__device__ __forceinline__ unsigned pk(float a, float b) {
  return __builtin_amdgcn_perm(__float_as_uint(a), __float_as_uint(b), 0x07060302u);
}
__device__ __forceinline__ float fexp(float x) { return __expf(x); }

__device__ __forceinline__ void load_clip_box(const float* boxes, int r, float* b) {
  b[0] = fminf(fmaxf(boxes[r * 4 + 0], 0.f), IMG_W_F);
  b[1] = fminf(fmaxf(boxes[r * 4 + 1], 0.f), IMG_H_F);
  b[2] = fminf(fmaxf(boxes[r * 4 + 2], 0.f), IMG_W_F);
  b[3] = fminf(fmaxf(boxes[r * 4 + 3], 0.f), IMG_H_F);
}

// ============ pack W_det -> frag-linear bf16; zero control words ============
// entry e: l=e&63, ct=(e>>6)&1, gs=e>>7
// holds B[k = gs*32 + (l>>4)*8 + j][col = ct*16 + (l&15)], j=0..7
__global__ __launch_bounds__(256) void wT_kernel(
    const float* __restrict__ Wd, uint4* __restrict__ Wfrag,
    int* __restrict__ ctrl) {
  const int e = blockIdx.x * 256 + threadIdx.x;     // 64 blocks -> 16384
  const int l = e & 63;
  const int ct = (e >> 6) & 1;
  const int gs = e >> 7;
  const int c = ct * 16 + (l & 15);
  const int k0 = gs * 32 + (l >> 4) * 8;
  float w[8];
  if (c < 21) {
#pragma unroll
    for (int j = 0; j < 8; j++) w[j] = Wd[(size_t)(k0 + j) * 21 + c];
  } else {
#pragma unroll
    for (int j = 0; j < 8; j++) w[j] = 0.f;
  }
  uint4 v;
  v.x = pk(w[1], w[0]); v.y = pk(w[3], w[2]);
  v.z = pk(w[5], w[4]); v.w = pk(w[7], w[6]);
  Wfrag[(gs * 2 + ct) * 64 + l] = v;
  if (e < 42) ctrl[e] = 0;                          // dsum[20] + nc[20] + done1 + done2
}

// ============ fused det GEMM + grid sync + in-LDS softmax scan + tail ============
// 256 blocks x 1024 thr (16 waves) -- exactly 1 block/CU on 256 CUs, provably
// all co-resident (16 waves <= 32/CU, VGPR capped at 128 by launch_bounds,
// LDS ~34 KB), so the done1 spin cannot deadlock.
// Block = 16 rows, full K=4096; wave w: K [w*256,(w+1)*256). After the 16-way
// LDS reduce, logits for the block's 16 rows live in LDS: dsum partials go out
// via device atomics, one grid-wide done-counter sync, then each block tests
// ITS OWN rows from LDS (no detlog round-trip, no single-CU scan). Cross-block
// data uses atomic RMW only (coherent point -> no stale-L2 hazard).
__global__ __launch_bounds__(1024) void detgemm_kernel(
    const float* __restrict__ x, const uint4* __restrict__ Wfrag,
    float* __restrict__ dsum, int* __restrict__ nc,
    int* __restrict__ done1, int* __restrict__ done2,
    int* __restrict__ cand_r, float* __restrict__ cand_d,
    const float* __restrict__ Wc, const float* __restrict__ b_cls,
    const float* __restrict__ boxes, float* __restrict__ out) {
  __shared__ float red[16 * 512];                   // 32 KB
  __shared__ float ex[320];
  __shared__ float sd[20];
  __shared__ int   snc[20];
  __shared__ int   s_last, s_total;

  const int t = threadIdx.x;
  const int w = t >> 6, l = t & 63;
  const int r16 = l & 15, q = l >> 4;
  const int r0 = blockIdx.x * 16;

  // ---- prefetch all A (16 rows x 256 K for this wave): 16 outstanding loads ----
  const float* xrow = x + (size_t)(r0 + r16) * D_N + w * 256 + q * 8;
  float4 a[16];
#pragma unroll
  for (int s = 0; s < 8; s++) {
    a[2 * s]     = *(const float4*)(xrow + s * 32);
    a[2 * s + 1] = *(const float4*)(xrow + s * 32 + 4);
  }

  f32x4 acc0 = {0.f, 0.f, 0.f, 0.f};
  f32x4 acc1 = {0.f, 0.f, 0.f, 0.f};
#pragma unroll
  for (int s = 0; s < 8; s++) {
    const int gs = w * 8 + s;
    union { uint4 u; bf16x8 v; } b0, b1;
    b0.u = Wfrag[(gs * 2 + 0) * 64 + l];
    b1.u = Wfrag[(gs * 2 + 1) * 64 + l];
    union { bf16x8 v; unsigned u[4]; } af;
    af.u[0] = pk(a[2 * s].y,     a[2 * s].x);
    af.u[1] = pk(a[2 * s].w,     a[2 * s].z);
    af.u[2] = pk(a[2 * s + 1].y, a[2 * s + 1].x);
    af.u[3] = pk(a[2 * s + 1].w, a[2 * s + 1].z);
    acc0 = __builtin_amdgcn_mfma_f32_16x16x32_bf16(af.v, b0.v, acc0, 0, 0, 0);
    acc1 = __builtin_amdgcn_mfma_f32_16x16x32_bf16(af.v, b1.v, acc1, 0, 0, 0);
  }

  // lane l, reg j holds D[row=q*4+j][col=ct*16+r16]; red layout [w][c][r]
  *(f32x4*)(&red[w * 512 + (0  + r16) * 16 + q * 4]) = acc0;
  *(f32x4*)(&red[w * 512 + (16 + r16) * 16 + q * 4]) = acc1;
  __syncthreads();
  if (t < 512) {                                    // t = c*16 + r
    float v = 0.f;
#pragma unroll
    for (int w2 = 0; w2 < 16; w2++) v += red[w2 * 512 + t];
    red[t] = v;                                     // each loc read only by its own thread
  }
  __syncthreads();
  if (t < 320) ex[t] = fexp(red[t]);                // classes 0..19 only
  __syncthreads();
  if (t < 20) {
    float s = 0.f;
#pragma unroll
    for (int r = 0; r < 16; r++) s += ex[t * 16 + r];
    atomicAdd(&dsum[t], s);
  }
  __syncthreads();                                  // drains this block's atomics (vmcnt0)

  // ---- grid-wide sync: all dsum partials in before any block scans ----
  if (t == 0) {
    atomicAdd(done1, 1);
    while (atomicAdd(done1, 0) < 256) __builtin_amdgcn_s_sleep(8);
  }
  __syncthreads();
  if (t < 20) sd[t] = atomicAdd(&dsum[t], 0.0f);    // coherent read
  __syncthreads();

  // ---- scan own 16 rows from LDS: dsm > TH is a superset of score > TH ----
  if (t < 320) {
    const int c = t >> 4, r = t & 15;
    float dsm = ex[t] / sd[c];
    if (dsm > SCORE_TH) {
      int p = atomicAdd(&nc[c], 1);
      if (p < 32) {
        atomicExch(&cand_r[c * 32 + p], r0 + r);
        atomicExch(&cand_d[c * 32 + p], dsm);
      }
    }
  }
  __syncthreads();                                  // drain candidate atomics
  if (t == 0) s_last = (atomicAdd(done2, 1) == 255) ? 1 : 0;
  __syncthreads();
  if (!s_last) return;

  // ================== tail (last block only) ==================
  if (t < 20) snc[t] = atomicAdd(&nc[t], 0);
  __syncthreads();
  if (t == 0) {
    int tot = 0;
#pragma unroll
    for (int c = 0; c < 20; c++) tot += (snc[c] > 32 ? 32 : snc[c]);
    s_total = tot;
  }
  __syncthreads();

  if (s_total == 0) {
    // fast path: all scores below threshold -> top_k of zeros = indices 0..99
    if (t < TOPK_N) {
      int prop = t / C_N;
      int cls = t - prop * C_N;
      float b[4]; load_clip_box(boxes, prop, b);
      out[t] = 0.f;
      out[TOPK_N + t * 4 + 0] = b[0];
      out[TOPK_N + t * 4 + 1] = b[1];
      out[TOPK_N + t * 4 + 2] = b[2];
      out[TOPK_N + t * 4 + 3] = b[3];
      out[TOPK_N * 5 + t] = (float)cls;
    }
    return;
  }

  // ---- rare path: exact scores (cls GEMV on demand), NMS, top-100 ----
  float* cand_s = red;                              // carve dead LDS
  int*   s_ki   = (int*)(red + 640);                // 512
  float* s_ks   = red + 1152;                       // 512
  float* sval   = red + 1664;                       // 100
  int*   sidx   = (int*)(red + 1764);               // 100
  int*   s_kc   = (int*)(red + 1864);

  if (t == 0) *s_kc = 0;
  if (t < TOPK_N) { sval[t] = 0.f; sidx[t] = 0; }
  __syncthreads();

  for (int slot = t; slot < 640; slot += 1024) {
    const int c = slot >> 5, i = slot & 31;
    int n = snc[c]; if (n > 32) n = 32;
    if (i < n) {
      const int rr = atomicAdd(&cand_r[slot], 0);
      float lg[21];
#pragma unroll
      for (int j = 0; j < 21; j++) lg[j] = b_cls[j];
      const float* xr = x + (size_t)rr * D_N;
      for (int k = 0; k < D_N; k++) {
        float xv = xr[k];
        const float* wr = Wc + (size_t)k * 21;
#pragma unroll
        for (int j = 0; j < 21; j++) lg[j] = fmaf(xv, wr[j], lg[j]);
      }
      float m = -1e30f;
#pragma unroll
      for (int j = 0; j < 21; j++) m = fmaxf(m, lg[j]);
      float s = 0.f;
#pragma unroll
      for (int j = 0; j < 21; j++) s += fexp(lg[j] - m);
      float p = fexp(lg[c] - m) / s;
      cand_s[slot] = p * atomicAdd(&cand_d[slot], 0.0f);
    }
  }
  __syncthreads();

  if (t < 20) {
    const int c = t;
    int n = snc[c]; if (n > 32) n = 32;
    float s[32]; int rr[32]; int n2 = 0;
    for (int i = 0; i < n; i++) {
      float sc = cand_s[c * 32 + i];
      if (sc > SCORE_TH) { s[n2] = sc; rr[n2] = atomicAdd(&cand_r[c * 32 + i], 0); n2++; }
    }
    for (int i = 1; i < n2; i++) {                  // score desc, tie -> row asc
      float si = s[i]; int ri = rr[i];
      int j = i - 1;
      while (j >= 0 && (s[j] < si || (s[j] == si && rr[j] > ri))) {
        s[j + 1] = s[j]; rr[j + 1] = rr[j]; j--;
      }
      s[j + 1] = si; rr[j + 1] = ri;
    }
    unsigned supp = 0;
    for (int i = 0; i < n2; i++) {
      if (supp & (1u << i)) continue;
      int g = atomicAdd(s_kc, 1);
      if (g < 512) { s_ki[g] = rr[i] * C_N + c; s_ks[g] = s[i]; }
      float bi[4]; load_clip_box(boxes, rr[i], bi);
      float ai = (bi[2] - bi[0]) * (bi[3] - bi[1]);
      for (int j = i + 1; j < n2; j++) {
        if (supp & (1u << j)) continue;
        float bj[4]; load_clip_box(boxes, rr[j], bj);
        float aj = (bj[2] - bj[0]) * (bj[3] - bj[1]);
        float lx = fmaxf(bi[0], bj[0]), ly = fmaxf(bi[1], bj[1]);
        float rx = fminf(bi[2], bj[2]), ry = fminf(bi[3], bj[3]);
        float wdt = fmaxf(rx - lx, 0.f), hgt = fmaxf(ry - ly, 0.f);
        float inter = wdt * hgt;
        float iou = inter / (ai + aj - inter + 1e-9f);
        if (iou > NMS_TH) supp |= (1u << j);
      }
    }
  }
  __syncthreads();

  // ---- top-100 with jax.lax.top_k tie rules ----
  int m = *s_kc; if (m > 512) m = 512;
  for (int i = t; i < m; i += 1024) {
    float si = s_ks[i]; int xi = s_ki[i];
    int rank = 0;
    for (int j = 0; j < m; j++) {
      float sj = s_ks[j]; int xj = s_ki[j];
      if (sj > si || (sj == si && xj < xi)) rank++;
    }
    if (rank < TOPK_N) { sval[rank] = si; sidx[rank] = xi; }
  }
  __syncthreads();
  if (t == 0) {
    int f = m < TOPK_N ? m : TOPK_N;
    int cur = 0;
    for (int slot = f; slot < TOPK_N; slot++) {
      for (;;) {
        bool member = false;
        for (int j = 0; j < m; j++)
          if (s_ki[j] == cur) { member = true; break; }
        if (!member) break;
        cur++;
      }
      sval[slot] = 0.f;
      sidx[slot] = cur;
      cur++;
    }
  }
  __syncthreads();
  if (t < TOPK_N) {
    int idx = sidx[t];
    int prop = idx / C_N;
    int cls = idx - prop * C_N;
    float b[4]; load_clip_box(boxes, prop, b);
    out[t] = sval[t];
    out[TOPK_N + t * 4 + 0] = b[0];
    out[TOPK_N + t * 4 + 1] = b[1];
    out[TOPK_N + t * 4 + 2] = b[2];
    out[TOPK_N + t * 4 + 3] = b[3];
    out[TOPK_N * 5 + t] = (float)cls;
  }
}

extern "C" void kernel_launch(void* const* d_in, const int* in_sizes, int n_in,
                              void* d_out, int out_size, void* d_ws, size_t ws_size,
                              hipStream_t stream) {
  const float* x     = (const float*)d_in[0];
  const float* boxes = (const float*)d_in[1];
  const float* W_cls = (const float*)d_in[2];
  const float* b_cls = (const float*)d_in[3];
  const float* W_det = (const float*)d_in[4];
  // b_det unused: column-softmax bias cancels

  float* out = (float*)d_out;
  float* ws = (float*)d_ws;
  uint4* Wfrag  = (uint4*)ws;
  float* dsum   = ws + CTRL_OFF;                    // 20 f32
  int*   nc     = (int*)(ws + CTRL_OFF) + 20;       // 20 i32
  int*   done1  = (int*)(ws + CTRL_OFF) + 40;
  int*   done2  = (int*)(ws + CTRL_OFF) + 41;
  int*   cand_r = (int*)(ws + CAND_R_OFF);
  float* cand_d = ws + CAND_D_OFF;

  wT_kernel     <<<64,  256,  0, stream>>>(W_det, Wfrag, (int*)(ws + CTRL_OFF));
  detgemm_kernel<<<256, 1024, 0, stream>>>(x, Wfrag, dsum, nc, done1, done2,
                                           cand_r, cand_d, W_cls, b_cls, boxes, out);
}

// Round 4
// 114.269 us; speedup vs baseline: 1.7215x; 1.0526x over previous
//
#include <hip/hip_runtime.h>
#include <math.h>

#define R_N 4096
#define D_N 4096
#define C_N 20
#define IMG_W_F 1216.0f
#define IMG_H_F 800.0f
#define SCORE_TH 0.05f
#define NMS_TH 0.5f
#define TOPK_N 100

// ---- workspace layout (units: 4-byte words) ----
// Wfrag: 128 gs x 2 ct x 64 lanes x 16 B = 256 KB (det cols 0..20, 21..31 zero)
#define WF_WORDS   (128 * 2 * 64 * 4)                // 65536
#define CTRL_OFF   (WF_WORDS)                        // dsum f32[20] | nc i32[20] | done1 | done2 (42, pad 64)
#define DETT_OFF   (CTRL_OFF + 64)                   // detT[2][20][4096] f32 partial logits
#define DETT_WORDS (2 * 20 * R_N)
#define CAND_R_OFF (DETT_OFF + DETT_WORDS)           // i32[640]
#define CAND_D_OFF (CAND_R_OFF + 640)                // f32[640]

typedef short bf16x8 __attribute__((ext_vector_type(8)));
typedef float f32x4  __attribute__((ext_vector_type(4)));

// truncating bf16 pack: {hi16(a), hi16(b)} -> lo short = bf16(b), hi short = bf16(a)
__device__ __forceinline__ unsigned pk(float a, float b) {
  return __builtin_amdgcn_perm(__float_as_uint(a), __float_as_uint(b), 0x07060302u);
}
__device__ __forceinline__ float fexp(float x) { return __expf(x); }

__device__ __forceinline__ void load_clip_box(const float* boxes, int r, float* b) {
  b[0] = fminf(fmaxf(boxes[r * 4 + 0], 0.f), IMG_W_F);
  b[1] = fminf(fmaxf(boxes[r * 4 + 1], 0.f), IMG_H_F);
  b[2] = fminf(fmaxf(boxes[r * 4 + 2], 0.f), IMG_W_F);
  b[3] = fminf(fmaxf(boxes[r * 4 + 3], 0.f), IMG_H_F);
}

// ============ pack W_det -> frag-linear bf16; zero control words ============
// entry e: l=e&63, ct=(e>>6)&1, gs=e>>7
// holds B[k = gs*32 + (l>>4)*8 + j][col = ct*16 + (l&15)], j=0..7
__global__ __launch_bounds__(128) void wT_kernel(
    const float* __restrict__ Wd, uint4* __restrict__ Wfrag,
    int* __restrict__ ctrl) {
  const int e = blockIdx.x * 128 + threadIdx.x;     // 128 blocks -> 16384
  const int l = e & 63;
  const int ct = (e >> 6) & 1;
  const int gs = e >> 7;
  const int c = ct * 16 + (l & 15);
  const int k0 = gs * 32 + (l >> 4) * 8;
  float w[8];
  if (c < 21) {
#pragma unroll
    for (int j = 0; j < 8; j++) w[j] = Wd[(size_t)(k0 + j) * 21 + c];
  } else {
#pragma unroll
    for (int j = 0; j < 8; j++) w[j] = 0.f;
  }
  uint4 v;
  v.x = pk(w[1], w[0]); v.y = pk(w[3], w[2]);
  v.z = pk(w[5], w[4]); v.w = pk(w[7], w[6]);
  Wfrag[(gs * 2 + ct) * 64 + l] = v;
  if (e < 64) ctrl[e] = 0;                          // dsum[20] + nc[20] + done1 + done2
}

// ============ det GEMM, 2-way K-split, no sync, no atomics ============
// 512 blocks x 1024 thr (16 waves) -> 2 blocks/CU, 32 waves/CU.
// Block (rblk,kb): rows [rblk*16,+16), K half kb; wave w: K [kb*2048+w*128,+128).
// A: all 8 float4 loads issued up front, pinned by sched_barrier(0) so the
// compiler can't sink them into the MFMA loop (round-3 VGPR=32 regression).
// B: frag-linear from L2. Epilogue: 16-way LDS reduce -> plain coalesced
// stores into per-half transposed plane detT[kb][c][r].
__global__ __launch_bounds__(1024) void detgemm_kernel(
    const float* __restrict__ x, const uint4* __restrict__ Wfrag,
    float* __restrict__ detT) {
  __shared__ float red[16 * 512];                   // 32 KB
  const int t = threadIdx.x;
  const int w = t >> 6, l = t & 63;
  const int r16 = l & 15, q = l >> 4;
  const int rblk = blockIdx.x >> 1;
  const int kb   = blockIdx.x & 1;
  const int r0 = rblk * 16;

  const float* xrow = x + (size_t)(r0 + r16) * D_N + kb * 2048 + w * 128 + q * 8;

  // ---- prefetch all A (this wave's 16 rows x 128 K): 8 outstanding loads ----
  float4 a[8];
#pragma unroll
  for (int s = 0; s < 4; s++) {
    a[2 * s]     = *(const float4*)(xrow + s * 32);
    a[2 * s + 1] = *(const float4*)(xrow + s * 32 + 4);
  }
  __builtin_amdgcn_sched_barrier(0);                // keep loads issued up-front

  f32x4 acc0 = {0.f, 0.f, 0.f, 0.f};
  f32x4 acc1 = {0.f, 0.f, 0.f, 0.f};
#pragma unroll
  for (int s = 0; s < 4; s++) {
    const int gs = kb * 64 + w * 4 + s;
    union { uint4 u; bf16x8 v; } b0, b1;
    b0.u = Wfrag[(gs * 2 + 0) * 64 + l];
    b1.u = Wfrag[(gs * 2 + 1) * 64 + l];
    union { bf16x8 v; unsigned u[4]; } af;
    af.u[0] = pk(a[2 * s].y,     a[2 * s].x);
    af.u[1] = pk(a[2 * s].w,     a[2 * s].z);
    af.u[2] = pk(a[2 * s + 1].y, a[2 * s + 1].x);
    af.u[3] = pk(a[2 * s + 1].w, a[2 * s + 1].z);
    acc0 = __builtin_amdgcn_mfma_f32_16x16x32_bf16(af.v, b0.v, acc0, 0, 0, 0);
    acc1 = __builtin_amdgcn_mfma_f32_16x16x32_bf16(af.v, b1.v, acc1, 0, 0, 0);
  }

  // lane l, reg j holds D[row = q*4+j][col = ct*16 + r16]; red layout [w][c][r]
  *(f32x4*)(&red[w * 512 + (0  + r16) * 16 + q * 4]) = acc0;
  *(f32x4*)(&red[w * 512 + (16 + r16) * 16 + q * 4]) = acc1;
  __syncthreads();
  if (t < 512) {                                    // t = c*16 + r
    float v = 0.f;
#pragma unroll
    for (int w2 = 0; w2 < 16; w2++) v += red[w2 * 512 + t];
    red[t] = v;
  }
  __syncthreads();
  if (t < 320) {                                    // classes 0..19 only
    const int c = t >> 4, r = t & 15;
    detT[(size_t)(kb * 20 + c) * R_N + r0 + r] = red[t];
  }
}

// ============ scan: 32 blocks x 1024, cheap 32-way sync, tail in last block ====
// Block b owns rows [b*128,+128): sums the two K-half planes, exp -> LDS,
// per-class partial sums -> dsum atomics; 32-block done-counter (polling with
// agent-scope atomic LOADS, not RMWs); candidate test from LDS; last block
// runs exact-score GEMV / NMS / top-100 (fast path when no candidates).
__global__ __launch_bounds__(1024) void scan_kernel(
    const float* __restrict__ x, const float* __restrict__ Wc,
    const float* __restrict__ b_cls, const float* __restrict__ detT,
    float* __restrict__ dsum, int* __restrict__ nc,
    int* __restrict__ done1, int* __restrict__ done2,
    int* __restrict__ cand_r, float* __restrict__ cand_d,
    const float* __restrict__ boxes, float* __restrict__ out) {
  __shared__ float sm[2560];                        // ex[c][r] in passes; tail scratch after
  __shared__ float sd[20];
  __shared__ int   snc[20];
  __shared__ int   s_last, s_total;
  const int t = threadIdx.x;
  const int rbase = blockIdx.x * 128;

  // ---- pass A: logits = half0 + half1; exp -> LDS; per-class sums ----
  for (int idx = t; idx < 2560; idx += 1024) {
    const int c = idx >> 7, r = idx & 127;
    float lg = detT[(size_t)c * R_N + rbase + r] +
               detT[(size_t)(20 + c) * R_N + rbase + r];
    sm[idx] = fexp(lg);
  }
  __syncthreads();
  if (t < 20) {
    float s = 0.f;
#pragma unroll
    for (int r = 0; r < 128; r++) s += sm[t * 128 + r];
    atomicAdd(&dsum[t], s);
  }
  __syncthreads();                                  // drains this block's atomics

  // ---- 32-block sync: poll with atomic loads (no RMW line ping-pong) ----
  if (t == 0) {
    __hip_atomic_fetch_add(done1, 1, __ATOMIC_RELEASE, __HIP_MEMORY_SCOPE_AGENT);
    while (__hip_atomic_load(done1, __ATOMIC_ACQUIRE, __HIP_MEMORY_SCOPE_AGENT) < 32)
      __builtin_amdgcn_s_sleep(2);
  }
  __syncthreads();
  if (t < 20) sd[t] = __hip_atomic_load(&dsum[t], __ATOMIC_RELAXED, __HIP_MEMORY_SCOPE_AGENT);
  __syncthreads();

  // ---- pass B: dsm > TH is a superset of score > TH (cls_sm <= 1) ----
  for (int idx = t; idx < 2560; idx += 1024) {
    const int c = idx >> 7, r = idx & 127;
    float dsm = sm[idx] / sd[c];
    if (dsm > SCORE_TH) {
      int p = atomicAdd(&nc[c], 1);
      if (p < 32) {
        atomicExch(&cand_r[c * 32 + p], rbase + r);
        atomicExch(&cand_d[c * 32 + p], dsm);
      }
    }
  }
  __syncthreads();                                  // drain candidate atomics
  if (t == 0)
    s_last = (__hip_atomic_fetch_add(done2, 1, __ATOMIC_ACQ_REL, __HIP_MEMORY_SCOPE_AGENT) == 31)
               ? 1 : 0;
  __syncthreads();
  if (!s_last) return;

  // ================== tail (last block only) ==================
  if (t < 20) snc[t] = __hip_atomic_load(&nc[t], __ATOMIC_RELAXED, __HIP_MEMORY_SCOPE_AGENT);
  __syncthreads();
  if (t == 0) {
    int tot = 0;
#pragma unroll
    for (int c = 0; c < 20; c++) tot += (snc[c] > 32 ? 32 : snc[c]);
    s_total = tot;
  }
  __syncthreads();

  if (s_total == 0) {
    // fast path: all scores below threshold -> top_k of zeros = indices 0..99
    if (t < TOPK_N) {
      int prop = t / C_N;
      int cls = t - prop * C_N;
      float b[4]; load_clip_box(boxes, prop, b);
      out[t] = 0.f;
      out[TOPK_N + t * 4 + 0] = b[0];
      out[TOPK_N + t * 4 + 1] = b[1];
      out[TOPK_N + t * 4 + 2] = b[2];
      out[TOPK_N + t * 4 + 3] = b[3];
      out[TOPK_N * 5 + t] = (float)cls;
    }
    return;
  }

  // ---- rare path: exact scores (cls GEMV on demand), NMS, top-100 ----
  float* cand_s = sm;                               // carve dead LDS
  int*   s_ki   = (int*)(sm + 640);                 // 512
  float* s_ks   = sm + 1152;                        // 512
  float* sval   = sm + 1664;                        // 100
  int*   sidx   = (int*)(sm + 1764);                // 100
  int*   s_kc   = (int*)(sm + 1864);

  if (t == 0) *s_kc = 0;
  if (t < TOPK_N) { sval[t] = 0.f; sidx[t] = 0; }
  __syncthreads();

  for (int slot = t; slot < 640; slot += 1024) {
    const int c = slot >> 5, i = slot & 31;
    int n = snc[c]; if (n > 32) n = 32;
    if (i < n) {
      const int rr = __hip_atomic_load(&cand_r[slot], __ATOMIC_RELAXED, __HIP_MEMORY_SCOPE_AGENT);
      float lg[21];
#pragma unroll
      for (int j = 0; j < 21; j++) lg[j] = b_cls[j];
      const float* xr = x + (size_t)rr * D_N;
      for (int k = 0; k < D_N; k++) {
        float xv = xr[k];
        const float* wr = Wc + (size_t)k * 21;
#pragma unroll
        for (int j = 0; j < 21; j++) lg[j] = fmaf(xv, wr[j], lg[j]);
      }
      float m = -1e30f;
#pragma unroll
      for (int j = 0; j < 21; j++) m = fmaxf(m, lg[j]);
      float s = 0.f;
#pragma unroll
      for (int j = 0; j < 21; j++) s += fexp(lg[j] - m);
      float p = fexp(lg[c] - m) / s;
      float dv = __hip_atomic_load(&cand_d[slot], __ATOMIC_RELAXED, __HIP_MEMORY_SCOPE_AGENT);
      cand_s[slot] = p * dv;
    }
  }
  __syncthreads();

  if (t < 20) {
    const int c = t;
    int n = snc[c]; if (n > 32) n = 32;
    float s[32]; int rr[32]; int n2 = 0;
    for (int i = 0; i < n; i++) {
      float sc = cand_s[c * 32 + i];
      if (sc > SCORE_TH) {
        s[n2] = sc;
        rr[n2] = __hip_atomic_load(&cand_r[c * 32 + i], __ATOMIC_RELAXED, __HIP_MEMORY_SCOPE_AGENT);
        n2++;
      }
    }
    for (int i = 1; i < n2; i++) {                  // score desc, tie -> row asc
      float si = s[i]; int ri = rr[i];
      int j = i - 1;
      while (j >= 0 && (s[j] < si || (s[j] == si && rr[j] > ri))) {
        s[j + 1] = s[j]; rr[j + 1] = rr[j]; j--;
      }
      s[j + 1] = si; rr[j + 1] = ri;
    }
    unsigned supp = 0;
    for (int i = 0; i < n2; i++) {
      if (supp & (1u << i)) continue;
      int g = atomicAdd(s_kc, 1);
      if (g < 512) { s_ki[g] = rr[i] * C_N + c; s_ks[g] = s[i]; }
      float bi[4]; load_clip_box(boxes, rr[i], bi);
      float ai = (bi[2] - bi[0]) * (bi[3] - bi[1]);
      for (int j = i + 1; j < n2; j++) {
        if (supp & (1u << j)) continue;
        float bj[4]; load_clip_box(boxes, rr[j], bj);
        float aj = (bj[2] - bj[0]) * (bj[3] - bj[1]);
        float lx = fmaxf(bi[0], bj[0]), ly = fmaxf(bi[1], bj[1]);
        float rx = fminf(bi[2], bj[2]), ry = fminf(bi[3], bj[3]);
        float wdt = fmaxf(rx - lx, 0.f), hgt = fmaxf(ry - ly, 0.f);
        float inter = wdt * hgt;
        float iou = inter / (ai + aj - inter + 1e-9f);
        if (iou > NMS_TH) supp |= (1u << j);
      }
    }
  }
  __syncthreads();

  // ---- top-100 with jax.lax.top_k tie rules ----
  int m = *s_kc; if (m > 512) m = 512;
  for (int i = t; i < m; i += 1024) {
    float si = s_ks[i]; int xi = s_ki[i];
    int rank = 0;
    for (int j = 0; j < m; j++) {
      float sj = s_ks[j]; int xj = s_ki[j];
      if (sj > si || (sj == si && xj < xi)) rank++;
    }
    if (rank < TOPK_N) { sval[rank] = si; sidx[rank] = xi; }
  }
  __syncthreads();
  if (t == 0) {
    int f = m < TOPK_N ? m : TOPK_N;
    int cur = 0;
    for (int slot = f; slot < TOPK_N; slot++) {
      for (;;) {
        bool member = false;
        for (int j = 0; j < m; j++)
          if (s_ki[j] == cur) { member = true; break; }
        if (!member) break;
        cur++;
      }
      sval[slot] = 0.f;
      sidx[slot] = cur;
      cur++;
    }
  }
  __syncthreads();
  if (t < TOPK_N) {
    int idx = sidx[t];
    int prop = idx / C_N;
    int cls = idx - prop * C_N;
    float b[4]; load_clip_box(boxes, prop, b);
    out[t] = sval[t];
    out[TOPK_N + t * 4 + 0] = b[0];
    out[TOPK_N + t * 4 + 1] = b[1];
    out[TOPK_N + t * 4 + 2] = b[2];
    out[TOPK_N + t * 4 + 3] = b[3];
    out[TOPK_N * 5 + t] = (float)cls;
  }
}

extern "C" void kernel_launch(void* const* d_in, const int* in_sizes, int n_in,
                              void* d_out, int out_size, void* d_ws, size_t ws_size,
                              hipStream_t stream) {
  const float* x     = (const float*)d_in[0];
  const float* boxes = (const float*)d_in[1];
  const float* W_cls = (const float*)d_in[2];
  const float* b_cls = (const float*)d_in[3];
  const float* W_det = (const float*)d_in[4];
  // b_det unused: column-softmax bias cancels

  float* out = (float*)d_out;
  float* ws = (float*)d_ws;
  uint4* Wfrag  = (uint4*)ws;
  float* dsum   = ws + CTRL_OFF;                    // 20 f32
  int*   nc     = (int*)(ws + CTRL_OFF) + 20;       // 20 i32
  int*   done1  = (int*)(ws + CTRL_OFF) + 40;
  int*   done2  = (int*)(ws + CTRL_OFF) + 41;
  float* detT   = ws + DETT_OFF;
  int*   cand_r = (int*)(ws + CAND_R_OFF);
  float* cand_d = ws + CAND_D_OFF;

  wT_kernel     <<<128, 128,  0, stream>>>(W_det, Wfrag, (int*)(ws + CTRL_OFF));
  detgemm_kernel<<<512, 1024, 0, stream>>>(x, Wfrag, detT);
  scan_kernel   <<<32,  1024, 0, stream>>>(x, W_cls, b_cls, detT, dsum, nc,
                                           done1, done2, cand_r, cand_d, boxes, out);
}